// Round 8
// baseline (279.028 us; speedup 1.0000x reference)
//
#include <hip/hip_runtime.h>

typedef unsigned short u16;
typedef unsigned int u32;
typedef __attribute__((ext_vector_type(8))) short short8;
typedef __attribute__((ext_vector_type(4))) short short4_t;
typedef __attribute__((ext_vector_type(4))) float float4_t;

#define T_SEQ 2048
#define DMODEL 1024
#define NH 16
#define HD 64

// async global->LDS, 16B per lane. LDS dest must be wave-uniform base + lane*16.
#define GLL16(g, l) __builtin_amdgcn_global_load_lds( \
    (const __attribute__((address_space(1))) u32*)(g), \
    (__attribute__((address_space(3))) u32*)(l), 16, 0, 0)

__device__ inline u16 f2b(float f) {  // fp32 -> bf16 RNE (finite inputs)
  u32 x = __builtin_bit_cast(u32, f);
  x += 0x7fffu + ((x >> 16) & 1u);
  return (u16)(x >> 16);
}

// Convert f32 inputs -> bf16 workspace copies. x: 8192x1024; 4 weights 1024x1024
// (stored contiguously in wb). 8 elems/thread, fully coalesced.
__global__ __launch_bounds__(256) void conv_f2b(
    const float* __restrict__ x, const float* __restrict__ wq,
    const float* __restrict__ wk, const float* __restrict__ wv,
    const float* __restrict__ wp, u16* __restrict__ xb, u16* __restrict__ wb) {
  const size_t SZc = (size_t)8192 * 1024, WSZc = (size_t)1024 * 1024;
  size_t i = ((size_t)blockIdx.x * 256 + threadIdx.x) * 8;
  const float* s; u16* d; size_t off;
  if (i < SZc) { s = x; d = xb; off = i; }
  else {
    size_t j = i - SZc;
    size_t w = j >> 20;            // WSZ = 2^20
    off = j & (WSZc - 1);
    s = (w == 0) ? wq : (w == 1) ? wk : (w == 2) ? wv : wp;
    d = wb + w * WSZc;
  }
  float4_t a = *(const float4_t*)(s + off);
  float4_t b = *(const float4_t*)(s + off + 4);
  short8 o;
  o[0] = (short)f2b(a[0]); o[1] = (short)f2b(a[1]);
  o[2] = (short)f2b(a[2]); o[3] = (short)f2b(a[3]);
  o[4] = (short)f2b(b[0]); o[5] = (short)f2b(b[1]);
  o[6] = (short)f2b(b[2]); o[7] = (short)f2b(b[3]);
  *(short8*)(d + off) = o;
}

// C[m][n] = sum_k A[m][k] * B[n][k]  (bf16 row-major, K contiguous).
// m97 K-loop. Operand-swapped MFMA (z != vtz): lane holds 4 CONSECUTIVE output
// cols at a fixed row (same verified C/D map, roles of A/B exchanged) ->
// float4 / short4 coalesced epilogue stores, register-only.
// z==vtz: unswapped; V written transposed per head (consecutive regs = t dim).
// z==scz: C scaled by cscale. of32: f32 row-major to Cf (output projection).
__global__ __launch_bounds__(256) void gemm_bt(
    const u16* __restrict__ A,
    const u16* __restrict__ B0, const u16* __restrict__ B1, const u16* __restrict__ B2,
    u16* __restrict__ C0, u16* __restrict__ C1, u16* __restrict__ C2,
    float* __restrict__ Cf,
    int N, int Kd, int vtz, int of32, int scz, float cscale)
{
  const u16* Bp = (blockIdx.z == 0) ? B0 : ((blockIdx.z == 1) ? B1 : B2);
  u16* Cp = (blockIdx.z == 0) ? C0 : ((blockIdx.z == 1) ? C1 : C2);
  const bool vt = ((int)blockIdx.z == vtz);
  const bool swp = !vt;  // swapped operands -> col-contiguous per-lane output
  const float cs = ((int)blockIdx.z == scz) ? cscale : 1.0f;
  __shared__ u16 As[128 * 32];
  __shared__ u16 Bs[128 * 32];
  const int tid = threadIdx.x;
  const int lane = tid & 63;
  const int li = lane & 15;
  const int quad = lane >> 4;
  const int wv = tid >> 6;
  const int wm = (wv >> 1) * 64;
  const int wn = (wv & 1) * 64;
  const size_t bm = (size_t)blockIdx.x * 128;
  const size_t bn = (size_t)blockIdx.y * 128;

  float4_t acc[4][4];
  const float4_t z4 = {0.f, 0.f, 0.f, 0.f};
#pragma unroll
  for (int i = 0; i < 4; i++)
#pragma unroll
    for (int j = 0; j < 4; j++) acc[i][j] = z4;

  const int c0 = tid, c1 = tid + 256;
  const int r0 = c0 >> 2, e0 = (c0 & 3) * 8;
  const int r1 = c1 >> 2, e1 = (c1 & 3) * 8;

  for (int k0 = 0; k0 < Kd; k0 += 32) {
    __syncthreads();
    GLL16(A + (bm + r0) * Kd + k0 + e0, &As[c0 * 8]);
    GLL16(A + (bm + r1) * Kd + k0 + e1, &As[c1 * 8]);
    GLL16(Bp + (bn + r0) * Kd + k0 + e0, &Bs[c0 * 8]);
    GLL16(Bp + (bn + r1) * Kd + k0 + e1, &Bs[c1 * 8]);
    __syncthreads();
    short8 af[4], bf[4];
#pragma unroll
    for (int i = 0; i < 4; i++)
      af[i] = *(const short8*)&As[(wm + i * 16 + li) * 32 + quad * 8];
#pragma unroll
    for (int j = 0; j < 4; j++)
      bf[j] = *(const short8*)&Bs[(wn + j * 16 + li) * 32 + quad * 8];
    if (swp) {
#pragma unroll
      for (int i = 0; i < 4; i++)
#pragma unroll
        for (int j = 0; j < 4; j++)
          acc[i][j] = __builtin_amdgcn_mfma_f32_16x16x32_bf16(bf[j], af[i], acc[i][j], 0, 0, 0);
    } else {
#pragma unroll
      for (int i = 0; i < 4; i++)
#pragma unroll
        for (int j = 0; j < 4; j++)
          acc[i][j] = __builtin_amdgcn_mfma_f32_16x16x32_bf16(af[i], bf[j], acc[i][j], 0, 0, 0);
    }
  }

  // C/D layout [measured m89/m91]: lane-col = lane&15, reg-row = quad*4 + r.
  // Unswapped: lane-col = output col n, reg-row = output row m.
  // Swapped:   lane-col = output ROW m,  reg-row = output COL n (contiguous!).
  if (of32) {
#pragma unroll
    for (int i = 0; i < 4; i++)
#pragma unroll
      for (int j = 0; j < 4; j++) {
        size_t row = bm + wm + (size_t)(i * 16 + li);
        size_t col = bn + wn + (size_t)(j * 16 + quad * 4);
        *(float4_t*)&Cf[row * (size_t)N + col] = acc[i][j];
      }
  } else if (!vt) {
#pragma unroll
    for (int i = 0; i < 4; i++)
#pragma unroll
      for (int j = 0; j < 4; j++) {
        size_t row = bm + wm + (size_t)(i * 16 + li);
        size_t col = bn + wn + (size_t)(j * 16 + quad * 4);
        short4_t o;
#pragma unroll
        for (int r = 0; r < 4; r++) o[r] = (short)f2b(acc[i][j][r] * cs);
        *(short4_t*)&Cp[row * (size_t)N + col] = o;
      }
  } else {
#pragma unroll
    for (int i = 0; i < 4; i++)
#pragma unroll
      for (int j = 0; j < 4; j++) {
        size_t row = bm + wm + (size_t)(i * 16 + quad * 4);
        size_t col = bn + wn + (size_t)(j * 16 + li);
        size_t bb = row >> 11;      // batch
        size_t tt = row & 2047;     // t within batch (multiple of 4)
        short4_t o;
#pragma unroll
        for (int r = 0; r < 4; r++) o[r] = (short)f2b(acc[i][j][r]);
        *(short4_t*)&Cp[(bb * 1024 + col) * 2048 + tt] = o;
      }
  }
}

// Flash attention, causal. grid (8, B*H), 512 threads = 8 waves x 16 queries.
// Constant-work pairing: block b does Q-tiles (15-b) then (b) = 36 K-tiles.
// Double-buffered K/V LDS (one barrier per tile) + deferred l_i reduction.
// Fixed softmax base m=0 (Q pre-scaled by log2e/8 in GEMM). S^T = K·Q^T via
// 16x16x32; P^T feeds 16x16x16bf16_1k PV from registers. V pre-transposed.
#define LROW 72
__global__ __launch_bounds__(512) void attn_fwd(const u16* __restrict__ Qb,
                                                const u16* __restrict__ Kb,
                                                const u16* __restrict__ Vtb,
                                                u16* __restrict__ Ob) {
  __shared__ u16 Qs[128 * LROW];
  __shared__ u16 Kds[2][64 * LROW];
  __shared__ u16 Vds[2][64 * LROW];
  const int bh = blockIdx.y;
  const int bidx = bh >> 4;
  const int tid = threadIdx.x;
  const int lane = tid & 63;
  const int wv = tid >> 6;        // 0..7
  const int li = lane & 15;
  const int quad = lane >> 4;
  const size_t qkBase = ((size_t)bidx * T_SEQ) * DMODEL + (size_t)(bh & 15) * HD;
  const size_t vBase = (size_t)bh * HD * T_SEQ;
  const int krow = tid >> 3;          // 0..63
  const int kc8 = (tid & 7) * 8;      // chunk-of-8 within row
  const int kld = krow * LROW + kc8;  // LDS slot (16B aligned: 72*2=144)
  const float4_t z4 = {0.f, 0.f, 0.f, 0.f};

#pragma unroll 1
  for (int ph = 0; ph < 2; ph++) {
    const int qblk = ph ? (int)blockIdx.x : (15 - (int)blockIdx.x);  // heavy first
    const int q0 = qblk * 128;
    const int ktmax = 2 * qblk + 1;
    const int qg0 = q0 + wv * 16;   // first query of this wave

    __syncthreads();  // prior phase's LDS use complete
    // stage Q tile: 128 rows x 64 d, stride 72
#pragma unroll
    for (int t = 0; t < 4; t++) {
      int slot = tid + t * 512;
      int row = slot >> 4, hc = slot & 15;
      *(short4_t*)&Qs[row * LROW + hc * 4] =
          *(const short4_t*)&Qb[qkBase + (size_t)(q0 + row) * DMODEL + hc * 4];
    }
    // load K/V tile 0 into regs
    short8 kpre = *(const short8*)&Kb[qkBase + (size_t)krow * DMODEL + kc8];
    short8 vpre = *(const short8*)&Vtb[vBase + (size_t)krow * T_SEQ + kc8];
    __syncthreads();  // Qs visible
    short8 qf[2];  // B-frag of S^T MFMA: n = query = li, k = d
    {
      const int row = wv * 16 + li;
#pragma unroll
      for (int s = 0; s < 2; s++)
        qf[s] = *(const short8*)&Qs[row * LROW + s * 32 + quad * 8];
    }
    // stage tile 0 into buf0; prefetch tile 1
    *(short8*)&Kds[0][kld] = kpre;
    *(short8*)&Vds[0][kld] = vpre;
    kpre = *(const short8*)&Kb[qkBase + (size_t)(64 + krow) * DMODEL + kc8];
    vpre = *(const short8*)&Vtb[vBase + (size_t)krow * T_SEQ + 64 + kc8];

    float4_t accO[4];  // O^T: row d = dt*16 + quad*4 + r, col = query li
#pragma unroll
    for (int dt = 0; dt < 4; dt++) accO[dt] = z4;
    float l_i = 0.f;

    for (int kt = 0; kt <= ktmax; kt++) {
      const int k0 = kt * 64;
      const int cb = kt & 1;
      __syncthreads();  // buf[cb] writes visible; readers of buf[cb^1] done
      if (kt < ktmax) {
        *(short8*)&Kds[cb ^ 1][kld] = kpre;
        *(short8*)&Vds[cb ^ 1][kld] = vpre;
        if (kt + 1 < ktmax) {
          const int kn = k0 + 128;
          kpre = *(const short8*)&Kb[qkBase + (size_t)(kn + krow) * DMODEL + kc8];
          vpre = *(const short8*)&Vtb[vBase + (size_t)krow * T_SEQ + kn + kc8];
        }
      }
      if (k0 > qg0 + 15) continue;  // tile fully above this wave's diagonal

      // S^T[j][i]: A-frag = K rows (m=j), B-frag = Q rows (n=i), k = d
      float4_t st[4];
#pragma unroll
      for (int jt = 0; jt < 4; jt++) {
        float4_t c4 = z4;
        const int row = jt * 16 + li;
#pragma unroll
        for (int s = 0; s < 2; s++) {
          short8 kf = *(const short8*)&Kds[cb][row * LROW + s * 32 + quad * 8];
          c4 = __builtin_amdgcn_mfma_f32_16x16x32_bf16(kf, qf[s], c4, 0, 0, 0);
        }
        st[jt] = c4;
      }

      // P = exp2(S') (Q pre-scaled); mask only on diagonal-overlapping tile
      short4_t pf[4];  // == B-frag of 16x16x16_1k (k = j = quad*4+r, n = li)
      if (k0 + 63 > qg0) {
        const int ig = qg0 + li;
#pragma unroll
        for (int jt = 0; jt < 4; jt++)
#pragma unroll
          for (int r = 0; r < 4; r++) {
            int jg = k0 + jt * 16 + quad * 4 + r;
            float p = (jg <= ig) ? __builtin_amdgcn_exp2f(st[jt][r]) : 0.f;
            l_i += p;
            pf[jt][r] = (short)(__builtin_bit_cast(u32, p) >> 16);
          }
      } else {
#pragma unroll
        for (int jt = 0; jt < 4; jt++)
#pragma unroll
          for (int r = 0; r < 4; r++) {
            float p = __builtin_amdgcn_exp2f(st[jt][r]);
            l_i += p;
            pf[jt][r] = (short)(__builtin_bit_cast(u32, p) >> 16);
          }
      }

      // O^T += V^T · P^T : A-frag from Vds (m = d = li, k = j = quad*4+i)
#pragma unroll
      for (int dt = 0; dt < 4; dt++) {
        const int d = dt * 16 + li;
#pragma unroll
        for (int jt = 0; jt < 4; jt++) {
          short4_t vf = *(const short4_t*)&Vds[cb][d * LROW + jt * 16 + quad * 4];
          accO[dt] = __builtin_amdgcn_mfma_f32_16x16x16bf16_1k(vf, pf[jt], accO[dt], 0, 0, 0);
        }
      }
    }

    l_i += __shfl_xor(l_i, 16);
    l_i += __shfl_xor(l_i, 32);
    const float inv = 1.f / l_i;
    const int orow = q0 + wv * 16 + li;
    const size_t obase = ((size_t)bidx * T_SEQ + orow) * DMODEL + (size_t)(bh & 15) * HD;
#pragma unroll
    for (int dt = 0; dt < 4; dt++) {
      short4_t o4;
#pragma unroll
      for (int r = 0; r < 4; r++) o4[r] = (short)f2b(accO[dt][r] * inv);
      *(short4_t*)&Ob[obase + dt * 16 + quad * 4] = o4;
    }
  }
}

extern "C" void kernel_launch(void* const* d_in, const int* in_sizes, int n_in,
                              void* d_out, int out_size, void* d_ws, size_t ws_size,
                              hipStream_t stream) {
  (void)in_sizes; (void)n_in; (void)out_size; (void)ws_size;
  const float* x  = (const float*)d_in[0];
  const float* Wq = (const float*)d_in[1];
  const float* Wk = (const float*)d_in[2];
  const float* Wv = (const float*)d_in[3];
  const float* Wp = (const float*)d_in[4];
  float* out = (float*)d_out;

  const size_t SZ  = (size_t)8192 * 1024;   // x / Q / K / Vt / ctx elems
  const size_t WSZ = (size_t)1024 * 1024;   // one weight matrix elems

  u16* xb  = (u16*)d_ws;          // bf16 x
  u16* wb  = xb + SZ;             // bf16 weights, 4x contiguous (q,k,v,p)
  u16* Q   = wb + 4 * WSZ;
  u16* Kp  = Q + SZ;
  u16* Vt  = Kp + SZ;             // per-head transposed V
  u16* ctx = Vt + SZ;             // total ws use: ~92 MB

  const float SC = 0.18033688011112042f;  // (1/sqrt(64)) * log2(e), folded into Q

  dim3 blk(256);
  conv_f2b<<<dim3((unsigned)((SZ + 4 * WSZ) / 8 / 256)), blk, 0, stream>>>(
      x, Wq, Wk, Wv, Wp, xb, wb);
  // QKV projections; z=2 (V) writes transposed per head; z=0 (Q) pre-scaled
  gemm_bt<<<dim3(64, 8, 3), blk, 0, stream>>>(
      xb, wb, wb + WSZ, wb + 2 * WSZ, Q, Kp, Vt, nullptr, DMODEL, DMODEL, 2, 0,
      0, SC);
  attn_fwd<<<dim3(8, 4 * NH), dim3(512), 0, stream>>>(Q, Kp, Vt, ctx);
  // output projection -> f32 d_out
  gemm_bt<<<dim3(64, 8, 1), blk, 0, stream>>>(
      ctx, wb + 3 * WSZ, nullptr, nullptr, nullptr, nullptr, nullptr, out,
      DMODEL, DMODEL, -1, 1, -1, 1.0f);
}

// Round 9
// 250.579 us; speedup vs baseline: 1.1135x; 1.1135x over previous
//
#include <hip/hip_runtime.h>

typedef unsigned short u16;
typedef unsigned int u32;
typedef __attribute__((ext_vector_type(8))) short short8;
typedef __attribute__((ext_vector_type(4))) short short4_t;
typedef __attribute__((ext_vector_type(4))) float float4_t;

#define T_SEQ 2048
#define DMODEL 1024
#define NH 16
#define HD 64

// async global->LDS, 16B per lane. LDS dest must be wave-uniform base + lane*16.
#define GLL16(g, l) __builtin_amdgcn_global_load_lds( \
    (const __attribute__((address_space(1))) u32*)(g), \
    (__attribute__((address_space(3))) u32*)(l), 16, 0, 0)

__device__ inline u16 f2b(float f) {  // fp32 -> bf16 RNE (finite inputs)
  u32 x = __builtin_bit_cast(u32, f);
  x += 0x7fffu + ((x >> 16) & 1u);
  return (u16)(x >> 16);
}

// Convert f32 inputs -> bf16 workspace copies. x: 8192x1024; 4 weights 1024x1024
// (stored contiguously in wb). 8 elems/thread, fully coalesced.
__global__ __launch_bounds__(256) void conv_f2b(
    const float* __restrict__ x, const float* __restrict__ wq,
    const float* __restrict__ wk, const float* __restrict__ wv,
    const float* __restrict__ wp, u16* __restrict__ xb, u16* __restrict__ wb) {
  const size_t SZc = (size_t)8192 * 1024, WSZc = (size_t)1024 * 1024;
  size_t i = ((size_t)blockIdx.x * 256 + threadIdx.x) * 8;
  const float* s; u16* d; size_t off;
  if (i < SZc) { s = x; d = xb; off = i; }
  else {
    size_t j = i - SZc;
    size_t w = j >> 20;            // WSZ = 2^20
    off = j & (WSZc - 1);
    s = (w == 0) ? wq : (w == 1) ? wk : (w == 2) ? wv : wp;
    d = wb + w * WSZc;
  }
  float4_t a = *(const float4_t*)(s + off);
  float4_t b = *(const float4_t*)(s + off + 4);
  short8 o;
  o[0] = (short)f2b(a[0]); o[1] = (short)f2b(a[1]);
  o[2] = (short)f2b(a[2]); o[3] = (short)f2b(a[3]);
  o[4] = (short)f2b(b[0]); o[5] = (short)f2b(b[1]);
  o[6] = (short)f2b(b[2]); o[7] = (short)f2b(b[3]);
  *(short8*)(d + off) = o;
}

// C[m][n] = sum_k A[m][k] * B[n][k]  (bf16 row-major, K contiguous).
// m97 K-loop with ALL-SWAPPED MFMA operands (single path -> low VGPR):
//   acc[i][j] = mfma(bf[j], af[i], acc) gives lane: fixed output row
//   m = i*16+li, 4 CONSECUTIVE output cols n = j*16+quad*4+r  [r8-verified].
// Epilogue branches only:
//   of32: float4 stores to Cf (proj). !vt: short4 bf16 row stores (Q/K).
//   vt:   scatter per-reg to Vt[(b*1024 + n)*2048 + t] (V).
__global__ __launch_bounds__(256) void gemm_bt(
    const u16* __restrict__ A,
    const u16* __restrict__ B0, const u16* __restrict__ B1, const u16* __restrict__ B2,
    u16* __restrict__ C0, u16* __restrict__ C1, u16* __restrict__ C2,
    float* __restrict__ Cf,
    int N, int Kd, int vtz, int of32, int scz, float cscale)
{
  const u16* Bp = (blockIdx.z == 0) ? B0 : ((blockIdx.z == 1) ? B1 : B2);
  u16* Cp = (blockIdx.z == 0) ? C0 : ((blockIdx.z == 1) ? C1 : C2);
  const bool vt = ((int)blockIdx.z == vtz);
  const float cs = ((int)blockIdx.z == scz) ? cscale : 1.0f;
  __shared__ u16 As[128 * 32];
  __shared__ u16 Bs[128 * 32];
  const int tid = threadIdx.x;
  const int lane = tid & 63;
  const int li = lane & 15;
  const int quad = lane >> 4;
  const int wv = tid >> 6;
  const int wm = (wv >> 1) * 64;
  const int wn = (wv & 1) * 64;
  const size_t bm = (size_t)blockIdx.x * 128;
  const size_t bn = (size_t)blockIdx.y * 128;

  float4_t acc[4][4];
  const float4_t z4 = {0.f, 0.f, 0.f, 0.f};
#pragma unroll
  for (int i = 0; i < 4; i++)
#pragma unroll
    for (int j = 0; j < 4; j++) acc[i][j] = z4;

  const int c0 = tid, c1 = tid + 256;
  const int r0 = c0 >> 2, e0 = (c0 & 3) * 8;
  const int r1 = c1 >> 2, e1 = (c1 & 3) * 8;

  for (int k0 = 0; k0 < Kd; k0 += 32) {
    __syncthreads();
    GLL16(A + (bm + r0) * Kd + k0 + e0, &As[c0 * 8]);
    GLL16(A + (bm + r1) * Kd + k0 + e1, &As[c1 * 8]);
    GLL16(Bp + (bn + r0) * Kd + k0 + e0, &Bs[c0 * 8]);
    GLL16(Bp + (bn + r1) * Kd + k0 + e1, &Bs[c1 * 8]);
    __syncthreads();
    short8 af[4], bf[4];
#pragma unroll
    for (int i = 0; i < 4; i++)
      af[i] = *(const short8*)&As[(wm + i * 16 + li) * 32 + quad * 8];
#pragma unroll
    for (int j = 0; j < 4; j++)
      bf[j] = *(const short8*)&Bs[(wn + j * 16 + li) * 32 + quad * 8];
#pragma unroll
    for (int i = 0; i < 4; i++)
#pragma unroll
      for (int j = 0; j < 4; j++)
        acc[i][j] = __builtin_amdgcn_mfma_f32_16x16x32_bf16(bf[j], af[i], acc[i][j], 0, 0, 0);
  }

  // Swapped C/D map [r8-verified]: lane li = output row m, reg = output col n.
  if (of32) {
#pragma unroll
    for (int i = 0; i < 4; i++)
#pragma unroll
      for (int j = 0; j < 4; j++) {
        size_t row = bm + wm + (size_t)(i * 16 + li);
        size_t col = bn + wn + (size_t)(j * 16 + quad * 4);
        *(float4_t*)&Cf[row * (size_t)N + col] = acc[i][j];
      }
  } else if (!vt) {
#pragma unroll
    for (int i = 0; i < 4; i++)
#pragma unroll
      for (int j = 0; j < 4; j++) {
        size_t row = bm + wm + (size_t)(i * 16 + li);
        size_t col = bn + wn + (size_t)(j * 16 + quad * 4);
        short4_t o;
#pragma unroll
        for (int r = 0; r < 4; r++) o[r] = (short)f2b(acc[i][j][r] * cs);
        *(short4_t*)&Cp[row * (size_t)N + col] = o;
      }
  } else {
    // V: row = token t (b*2048 + tt), cols = feature n; write
    // Vt[(b*1024 + n)*2048 + tt] -> 4 scalar stores at stride 2048, lanes
    // li=0..15 give 32B-contiguous tt segments per store inst.
#pragma unroll
    for (int i = 0; i < 4; i++) {
      size_t row = bm + wm + (size_t)(i * 16 + li);
      size_t bb = row >> 11;        // batch
      size_t tt = row & 2047;       // t within batch
#pragma unroll
      for (int j = 0; j < 4; j++) {
        size_t col = bn + wn + (size_t)(j * 16 + quad * 4);
#pragma unroll
        for (int r = 0; r < 4; r++)
          Cp[(bb * 1024 + col + r) * 2048 + tt] = f2b(acc[i][j][r]);
      }
    }
  }
}

// Flash attention, causal. grid (8, B*H), 512 threads = 8 waves x 16 queries.
// Constant-work pairing: block b does Q-tiles (15-b) then (b) = 36 K-tiles.
// Double-buffered K/V LDS (one barrier per tile) + deferred l_i reduction.
// Fixed softmax base m=0 (Q pre-scaled by log2e/8 in GEMM). S^T = K·Q^T via
// 16x16x32; P^T feeds 16x16x16bf16_1k PV from registers. V pre-transposed.
#define LROW 72
__global__ __launch_bounds__(512) void attn_fwd(const u16* __restrict__ Qb,
                                                const u16* __restrict__ Kb,
                                                const u16* __restrict__ Vtb,
                                                u16* __restrict__ Ob) {
  __shared__ u16 Qs[128 * LROW];
  __shared__ u16 Kds[2][64 * LROW];
  __shared__ u16 Vds[2][64 * LROW];
  const int bh = blockIdx.y;
  const int bidx = bh >> 4;
  const int tid = threadIdx.x;
  const int lane = tid & 63;
  const int wv = tid >> 6;        // 0..7
  const int li = lane & 15;
  const int quad = lane >> 4;
  const size_t qkBase = ((size_t)bidx * T_SEQ) * DMODEL + (size_t)(bh & 15) * HD;
  const size_t vBase = (size_t)bh * HD * T_SEQ;
  const int krow = tid >> 3;          // 0..63
  const int kc8 = (tid & 7) * 8;      // chunk-of-8 within row
  const int kld = krow * LROW + kc8;  // LDS slot (16B aligned: 72*2=144)
  const float4_t z4 = {0.f, 0.f, 0.f, 0.f};

#pragma unroll 1
  for (int ph = 0; ph < 2; ph++) {
    const int qblk = ph ? (int)blockIdx.x : (15 - (int)blockIdx.x);  // heavy first
    const int q0 = qblk * 128;
    const int ktmax = 2 * qblk + 1;
    const int qg0 = q0 + wv * 16;   // first query of this wave

    __syncthreads();  // prior phase's LDS use complete
    // stage Q tile: 128 rows x 64 d, stride 72
#pragma unroll
    for (int t = 0; t < 4; t++) {
      int slot = tid + t * 512;
      int row = slot >> 4, hc = slot & 15;
      *(short4_t*)&Qs[row * LROW + hc * 4] =
          *(const short4_t*)&Qb[qkBase + (size_t)(q0 + row) * DMODEL + hc * 4];
    }
    // load K/V tile 0 into regs
    short8 kpre = *(const short8*)&Kb[qkBase + (size_t)krow * DMODEL + kc8];
    short8 vpre = *(const short8*)&Vtb[vBase + (size_t)krow * T_SEQ + kc8];
    __syncthreads();  // Qs visible
    short8 qf[2];  // B-frag of S^T MFMA: n = query = li, k = d
    {
      const int row = wv * 16 + li;
#pragma unroll
      for (int s = 0; s < 2; s++)
        qf[s] = *(const short8*)&Qs[row * LROW + s * 32 + quad * 8];
    }
    // stage tile 0 into buf0; prefetch tile 1
    *(short8*)&Kds[0][kld] = kpre;
    *(short8*)&Vds[0][kld] = vpre;
    kpre = *(const short8*)&Kb[qkBase + (size_t)(64 + krow) * DMODEL + kc8];
    vpre = *(const short8*)&Vtb[vBase + (size_t)krow * T_SEQ + 64 + kc8];

    float4_t accO[4];  // O^T: row d = dt*16 + quad*4 + r, col = query li
#pragma unroll
    for (int dt = 0; dt < 4; dt++) accO[dt] = z4;
    float l_i = 0.f;

    for (int kt = 0; kt <= ktmax; kt++) {
      const int k0 = kt * 64;
      const int cb = kt & 1;
      __syncthreads();  // buf[cb] writes visible; readers of buf[cb^1] done
      if (kt < ktmax) {
        *(short8*)&Kds[cb ^ 1][kld] = kpre;
        *(short8*)&Vds[cb ^ 1][kld] = vpre;
        if (kt + 1 < ktmax) {
          const int kn = k0 + 128;
          kpre = *(const short8*)&Kb[qkBase + (size_t)(kn + krow) * DMODEL + kc8];
          vpre = *(const short8*)&Vtb[vBase + (size_t)krow * T_SEQ + kn + kc8];
        }
      }
      if (k0 > qg0 + 15) continue;  // tile fully above this wave's diagonal

      // S^T[j][i]: A-frag = K rows (m=j), B-frag = Q rows (n=i), k = d
      float4_t st[4];
#pragma unroll
      for (int jt = 0; jt < 4; jt++) {
        float4_t c4 = z4;
        const int row = jt * 16 + li;
#pragma unroll
        for (int s = 0; s < 2; s++) {
          short8 kf = *(const short8*)&Kds[cb][row * LROW + s * 32 + quad * 8];
          c4 = __builtin_amdgcn_mfma_f32_16x16x32_bf16(kf, qf[s], c4, 0, 0, 0);
        }
        st[jt] = c4;
      }

      // P = exp2(S') (Q pre-scaled); mask only on diagonal-overlapping tile
      short4_t pf[4];  // == B-frag of 16x16x16_1k (k = j = quad*4+r, n = li)
      if (k0 + 63 > qg0) {
        const int ig = qg0 + li;
#pragma unroll
        for (int jt = 0; jt < 4; jt++)
#pragma unroll
          for (int r = 0; r < 4; r++) {
            int jg = k0 + jt * 16 + quad * 4 + r;
            float p = (jg <= ig) ? __builtin_amdgcn_exp2f(st[jt][r]) : 0.f;
            l_i += p;
            pf[jt][r] = (short)(__builtin_bit_cast(u32, p) >> 16);
          }
      } else {
#pragma unroll
        for (int jt = 0; jt < 4; jt++)
#pragma unroll
          for (int r = 0; r < 4; r++) {
            float p = __builtin_amdgcn_exp2f(st[jt][r]);
            l_i += p;
            pf[jt][r] = (short)(__builtin_bit_cast(u32, p) >> 16);
          }
      }

      // O^T += V^T · P^T : A-frag from Vds (m = d = li, k = j = quad*4+i)
#pragma unroll
      for (int dt = 0; dt < 4; dt++) {
        const int d = dt * 16 + li;
#pragma unroll
        for (int jt = 0; jt < 4; jt++) {
          short4_t vf = *(const short4_t*)&Vds[cb][d * LROW + jt * 16 + quad * 4];
          accO[dt] = __builtin_amdgcn_mfma_f32_16x16x16bf16_1k(vf, pf[jt], accO[dt], 0, 0, 0);
        }
      }
    }

    l_i += __shfl_xor(l_i, 16);
    l_i += __shfl_xor(l_i, 32);
    const float inv = 1.f / l_i;
    const int orow = q0 + wv * 16 + li;
    const size_t obase = ((size_t)bidx * T_SEQ + orow) * DMODEL + (size_t)(bh & 15) * HD;
#pragma unroll
    for (int dt = 0; dt < 4; dt++) {
      short4_t o4;
#pragma unroll
      for (int r = 0; r < 4; r++) o4[r] = (short)f2b(accO[dt][r] * inv);
      *(short4_t*)&Ob[obase + dt * 16 + quad * 4] = o4;
    }
  }
}

extern "C" void kernel_launch(void* const* d_in, const int* in_sizes, int n_in,
                              void* d_out, int out_size, void* d_ws, size_t ws_size,
                              hipStream_t stream) {
  (void)in_sizes; (void)n_in; (void)out_size; (void)ws_size;
  const float* x  = (const float*)d_in[0];
  const float* Wq = (const float*)d_in[1];
  const float* Wk = (const float*)d_in[2];
  const float* Wv = (const float*)d_in[3];
  const float* Wp = (const float*)d_in[4];
  float* out = (float*)d_out;

  const size_t SZ  = (size_t)8192 * 1024;   // x / Q / K / Vt / ctx elems
  const size_t WSZ = (size_t)1024 * 1024;   // one weight matrix elems

  u16* xb  = (u16*)d_ws;          // bf16 x
  u16* wb  = xb + SZ;             // bf16 weights, 4x contiguous (q,k,v,p)
  u16* Q   = wb + 4 * WSZ;
  u16* Kp  = Q + SZ;
  u16* Vt  = Kp + SZ;             // per-head transposed V
  u16* ctx = Vt + SZ;             // total ws use: ~92 MB

  const float SC = 0.18033688011112042f;  // (1/sqrt(64)) * log2(e), folded into Q

  dim3 blk(256);
  conv_f2b<<<dim3((unsigned)((SZ + 4 * WSZ) / 8 / 256)), blk, 0, stream>>>(
      x, Wq, Wk, Wv, Wp, xb, wb);
  // QKV projections; z=2 (V) writes transposed per head; z=0 (Q) pre-scaled
  gemm_bt<<<dim3(64, 8, 3), blk, 0, stream>>>(
      xb, wb, wb + WSZ, wb + 2 * WSZ, Q, Kp, Vt, nullptr, DMODEL, DMODEL, 2, 0,
      0, SC);
  attn_fwd<<<dim3(8, 4 * NH), dim3(512), 0, stream>>>(Q, Kp, Vt, ctx);
  // output projection -> f32 d_out
  gemm_bt<<<dim3(64, 8, 1), blk, 0, stream>>>(
      ctx, wb + 3 * WSZ, nullptr, nullptr, nullptr, nullptr, nullptr, out,
      DMODEL, DMODEL, -1, 1, -1, 1.0f);
}